// Round 3
// baseline (459.379 us; speedup 1.0000x reference)
//
#include <hip/hip_runtime.h>

// Fused LSTM (B=4096,T=365,F=32,H=50,relu cell) + dense head. v3.
// 256 blocks x 512 thr (8 waves); block owns 16 batch rows, 365 serial steps.
// vs v2:
//  - MFMA operands SWAPPED: D = (act . W)^T, so each lane's 4 acc regs are the
//    4 gates [i,f,c,o] of one unit (gate-permuted cols) for one batch row ->
//    gate phase fully in-register, Gs LDS roundtrip deleted.
//  - raw "s_waitcnt lgkmcnt(0); s_barrier" (no vmcnt drain) -> x prefetch
//    actually stays in flight across step barriers.
//  - 8 waves (w<5 own tiles {w, w+8}, else {w}) halves per-lane gate work.

typedef _Float16 f16;
typedef f16 f16x4 __attribute__((ext_vector_type(4)));
typedef float f32x4 __attribute__((ext_vector_type(4)));

#define T_STEPS 365
#define F_IN    32
#define H_U     50
#define NG      200
#define AST     72    // halves per As row

__global__ __launch_bounds__(512)
void lstm_fused(const float* __restrict__ x,
                const float* __restrict__ wk,
                const float* __restrict__ wr,
                const float* __restrict__ bias,
                const float* __restrict__ dw,
                const float* __restrict__ db,
                float* __restrict__ out)
{
    __shared__ f16 As[2][16 * AST];   // [buf][row][k']: k'=0..49 h, 50 = 1.0 (bias), 51..63 = 0

    const int tid  = threadIdx.x;
    const int lane = tid & 63;
    const int w    = tid >> 6;          // wave 0..7
    const int cl   = lane & 15;         // frag non-K index; D: batch row
    const int lg   = lane >> 4;         // frag K group; D: gate-col group
    const long row0 = (long)blockIdx.x * 16;

    const int n0 = w;                   // first owned tile
    const int n1 = w + 8;               // second owned tile (waves 0..4)
    const bool has1 = (w < 5);

    // ---- persistent gate-permuted W fragments (A-operand role) ----
    // within-tile col index = cl; col' = 16n+cl -> u = 4n+(cl>>2), g = cl&3
    // orig col = g*50 + u  (keras gate blocks [i,f,c,o])
    f16x4 bf0[6], bf1[6];
    {
        const int u0 = 4 * n0 + (cl >> 2);
        const int u1 = 4 * n1 + (cl >> 2);
        const int g  = cl & 3;
        const int c0 = g * H_U + u0;              // always valid (u0 <= 31)
        const int c1 = g * H_U + u1;
        const bool v1ok = has1 && (u1 < H_U);
        #pragma unroll
        for (int ks = 0; ks < 6; ++ks) {
            f16x4 v0, v1;
            #pragma unroll
            for (int e = 0; e < 4; ++e) {
                const int k = ks * 16 + lg * 4 + e;
                float w0 = 0.f, w1 = 0.f;
                if (k < 32)       { w0 = wk[k * NG + c0];        if (v1ok) w1 = wk[k * NG + c1]; }
                else if (k < 82)  { w0 = wr[(k - 32) * NG + c0]; if (v1ok) w1 = wr[(k - 32) * NG + c1]; }
                else if (k == 82) { w0 = bias[c0];               if (v1ok) w1 = bias[c1]; }
                v0[e] = (f16)w0; v1[e] = (f16)w1;
            }
            bf0[ks] = v0; bf1[ks] = v1;
        }
    }

    // ---- init LDS ----
    for (int i = tid; i < 16 * AST; i += 512) { As[0][i] = (f16)0.f; As[1][i] = (f16)0.f; }
    __syncthreads();
    if (tid < 16) { As[0][tid * AST + 50] = (f16)1.f; As[1][tid * AST + 50] = (f16)1.f; }
    __syncthreads();

    // ---- x prefetch pipeline (depth 2, manual A/B reg buffers) ----
    const float* xrow = x + (row0 + cl) * (long)(T_STEPS * F_IN);
    float4 xlA = *(const float4*)(xrow + 0 * F_IN + 4 * lg);
    float4 xhA = *(const float4*)(xrow + 0 * F_IN + 4 * lg + 16);
    float4 xlB = *(const float4*)(xrow + 1 * F_IN + 4 * lg);
    float4 xhB = *(const float4*)(xrow + 1 * F_IN + 4 * lg + 16);

    float c0 = 0.f, c1 = 0.f;           // cell state: (row=cl, unit=4n+lg)
    const int u_0 = 4 * n0 + lg;        // always < 50
    const int u_1 = 4 * n1 + lg;        // guard < 50
    const bool wr1 = has1 && (u_1 < H_U);

    auto step = [&](int t, float4& xl, float4& xh) {
        const int p = t & 1;
        // activation fragments (B-operand role): x from regs, h from LDS
        f16x4 a0, a1, ah[4];
        #pragma unroll
        for (int jp = 0; jp < 4; ++jp)
            ah[jp] = *(const f16x4*)&As[p][cl * AST + 16 * jp + 4 * lg];
        a0[0] = (f16)xl.x; a0[1] = (f16)xl.y; a0[2] = (f16)xl.z; a0[3] = (f16)xl.w;
        a1[0] = (f16)xh.x; a1[1] = (f16)xh.y; a1[2] = (f16)xh.z; a1[3] = (f16)xh.w;
        // prefetch x(t+2) (stays in flight across the raw barrier)
        if (t + 2 < T_STEPS) {
            xl = *(const float4*)(xrow + (t + 2) * F_IN + 4 * lg);
            xh = *(const float4*)(xrow + (t + 2) * F_IN + 4 * lg + 16);
        }
        // D = (act . W)^T : acc[e] = gate e of unit 4n+lg, batch row cl
        f32x4 acc0 = {0.f, 0.f, 0.f, 0.f};
        acc0 = __builtin_amdgcn_mfma_f32_16x16x16f16(bf0[0], a0,    acc0, 0, 0, 0);
        acc0 = __builtin_amdgcn_mfma_f32_16x16x16f16(bf0[1], a1,    acc0, 0, 0, 0);
        acc0 = __builtin_amdgcn_mfma_f32_16x16x16f16(bf0[2], ah[0], acc0, 0, 0, 0);
        acc0 = __builtin_amdgcn_mfma_f32_16x16x16f16(bf0[3], ah[1], acc0, 0, 0, 0);
        acc0 = __builtin_amdgcn_mfma_f32_16x16x16f16(bf0[4], ah[2], acc0, 0, 0, 0);
        acc0 = __builtin_amdgcn_mfma_f32_16x16x16f16(bf0[5], ah[3], acc0, 0, 0, 0);
        f32x4 acc1 = {0.f, 0.f, 0.f, 0.f};
        if (has1) {
            acc1 = __builtin_amdgcn_mfma_f32_16x16x16f16(bf1[0], a0,    acc1, 0, 0, 0);
            acc1 = __builtin_amdgcn_mfma_f32_16x16x16f16(bf1[1], a1,    acc1, 0, 0, 0);
            acc1 = __builtin_amdgcn_mfma_f32_16x16x16f16(bf1[2], ah[0], acc1, 0, 0, 0);
            acc1 = __builtin_amdgcn_mfma_f32_16x16x16f16(bf1[3], ah[1], acc1, 0, 0, 0);
            acc1 = __builtin_amdgcn_mfma_f32_16x16x16f16(bf1[4], ah[2], acc1, 0, 0, 0);
            acc1 = __builtin_amdgcn_mfma_f32_16x16x16f16(bf1[5], ah[3], acc1, 0, 0, 0);
        }
        // gates fully in-register
        {
            const float ig = __builtin_amdgcn_rcpf(1.f + __expf(-acc0[0]));
            const float fg = __builtin_amdgcn_rcpf(1.f + __expf(-acc0[1]));
            const float cd = fmaxf(acc0[2], 0.f);
            const float og = __builtin_amdgcn_rcpf(1.f + __expf(-acc0[3]));
            c0 = fg * c0 + ig * cd;
            As[p ^ 1][cl * AST + u_0] = (f16)(og * fmaxf(c0, 0.f));
        }
        if (wr1) {
            const float ig = __builtin_amdgcn_rcpf(1.f + __expf(-acc1[0]));
            const float fg = __builtin_amdgcn_rcpf(1.f + __expf(-acc1[1]));
            const float cd = fmaxf(acc1[2], 0.f);
            const float og = __builtin_amdgcn_rcpf(1.f + __expf(-acc1[3]));
            c1 = fg * c1 + ig * cd;
            As[p ^ 1][cl * AST + u_1] = (f16)(og * fmaxf(c1, 0.f));
        }
        // raw barrier: drain LDS only, leave x prefetch (vmcnt) in flight
        asm volatile("s_waitcnt lgkmcnt(0)\n\ts_barrier" ::: "memory");
    };

    for (int m = 0; m < (T_STEPS - 1) / 2; ++m) {
        step(2 * m,     xlA, xhA);
        step(2 * m + 1, xlB, xhB);
    }
    step(T_STEPS - 1, xlA, xhA);   // t=364 even -> uses A regs (loaded at t=362)

    // ---- dense head: h_last in As[1] (last step wrote p^1 = 1) ----
    if (tid < 16) {
        float acc = db[0];
        #pragma unroll
        for (int u = 0; u < H_U; ++u)
            acc += (float)As[1][tid * AST + u] * dw[u];
        out[row0 + tid] = acc;
    }
}

extern "C" void kernel_launch(void* const* d_in, const int* in_sizes, int n_in,
                              void* d_out, int out_size, void* d_ws, size_t ws_size,
                              hipStream_t stream) {
    (void)in_sizes; (void)n_in; (void)d_ws; (void)ws_size; (void)out_size;
    const float* x  = (const float*)d_in[0];
    const float* wk = (const float*)d_in[1];
    const float* wr = (const float*)d_in[2];
    const float* bs = (const float*)d_in[3];
    const float* dw = (const float*)d_in[4];
    const float* db = (const float*)d_in[5];
    float* out = (float*)d_out;
    hipLaunchKernelGGL(lstm_fused, dim3(4096 / 16), dim3(512), 0, stream,
                       x, wk, wr, bs, dw, db, out);
}